// Round 1
// baseline (91.569 us; speedup 1.0000x reference)
//
#include <hip/hip_runtime.h>

// out = 0.5f * (3a - b - c - d) over 2x2 input blocks.
// x: (32,3,1024,1024) f32  ->  out: (32,3,512,512) f32
// Each thread: 2 output pixels = one float4 from even row + one float4 from odd row.

__global__ __launch_bounds__(256) void WaveletTransform_26104811225175_kernel(
    const float* __restrict__ in, float* __restrict__ out, int n_pairs) {
    int p = blockIdx.x * blockDim.x + threadIdx.x;
    if (p >= n_pairs) return;

    int jp   = p & 255;        // pair index within output row (256 pairs of 2 cols = 512 cols)
    int rest = p >> 8;
    int i    = rest & 511;     // output row (512)
    int bc   = rest >> 9;      // fused batch*channel (96)

    size_t in_base  = ((size_t)bc << 20) + ((size_t)(i << 1) << 10) + ((size_t)jp << 2);
    size_t out_base = ((size_t)bc << 18) + ((size_t)i << 9) + ((size_t)jp << 1);

    float4 top = *reinterpret_cast<const float4*>(in + in_base);          // a0 b0 a1 b1
    float4 bot = *reinterpret_cast<const float4*>(in + in_base + 1024);   // c0 d0 c1 d1

    float2 r;
    r.x = 0.5f * (3.0f * top.x - top.y - bot.x - bot.y);
    r.y = 0.5f * (3.0f * top.z - top.w - bot.z - bot.w);

    *reinterpret_cast<float2*>(out + out_base) = r;
}

extern "C" void kernel_launch(void* const* d_in, const int* in_sizes, int n_in,
                              void* d_out, int out_size, void* d_ws, size_t ws_size,
                              hipStream_t stream) {
    const float* in = (const float*)d_in[0];
    float* out = (float*)d_out;

    // total output pixels = 32*3*512*512 = 25,165,824 ; pairs = 12,582,912
    const int n_pairs = 32 * 3 * 512 * 256;
    const int block = 256;
    const int grid = (n_pairs + block - 1) / block;  // 49152

    WaveletTransform_26104811225175_kernel<<<grid, block, 0, stream>>>(in, out, n_pairs);
}

// Round 4
// 89.666 us; speedup vs baseline: 1.0212x; 1.0212x over previous
//
#include <hip/hip_runtime.h>

// out = 0.5f * (3a - b - c - d) over 2x2 input blocks.
// x: (32,3,1024,1024) f32  ->  out: (32,3,512,512) f32
// Each thread: 4 output pixels = 2x 16B nontemporal load from even row + 2x from
// odd row, one PLAIN 16B store. (Nontemporal store broke post-timing validation:
// nt writes bypass L2/LLC, readback saw stale 0xAA poison lines. Loads are safe —
// input is static/read-only.)

typedef float f32x4 __attribute__((ext_vector_type(4)));

__global__ __launch_bounds__(256) void WaveletTransform_26104811225175_kernel(
    const float* __restrict__ in, float* __restrict__ out, int n_quads) {
    int p = blockIdx.x * blockDim.x + threadIdx.x;
    if (p >= n_quads) return;

    int jq   = p & 127;        // quad index within output row (128 quads of 4 cols = 512 cols)
    int rest = p >> 7;
    int i    = rest & 511;     // output row (512)
    int bc   = rest >> 9;      // fused batch*channel (96)

    size_t in_base  = ((size_t)bc << 20) + ((size_t)(i << 1) << 10) + ((size_t)jq << 3);
    size_t out_base = ((size_t)bc << 18) + ((size_t)i << 9) + ((size_t)jq << 2);

    const f32x4* tp0 = reinterpret_cast<const f32x4*>(in + in_base);
    const f32x4* tp1 = reinterpret_cast<const f32x4*>(in + in_base + 4);
    const f32x4* bp0 = reinterpret_cast<const f32x4*>(in + in_base + 1024);
    const f32x4* bp1 = reinterpret_cast<const f32x4*>(in + in_base + 1028);

    f32x4 t0 = __builtin_nontemporal_load(tp0);   // a0 b0 a1 b1
    f32x4 t1 = __builtin_nontemporal_load(tp1);   // a2 b2 a3 b3
    f32x4 b0 = __builtin_nontemporal_load(bp0);   // c0 d0 c1 d1
    f32x4 b1 = __builtin_nontemporal_load(bp1);   // c2 d2 c3 d3

    f32x4 r;
    r.x = 0.5f * (3.0f * t0.x - t0.y - b0.x - b0.y);
    r.y = 0.5f * (3.0f * t0.z - t0.w - b0.z - b0.w);
    r.z = 0.5f * (3.0f * t1.x - t1.y - b1.x - b1.y);
    r.w = 0.5f * (3.0f * t1.z - t1.w - b1.z - b1.w);

    *reinterpret_cast<f32x4*>(out + out_base) = r;
}

extern "C" void kernel_launch(void* const* d_in, const int* in_sizes, int n_in,
                              void* d_out, int out_size, void* d_ws, size_t ws_size,
                              hipStream_t stream) {
    const float* in = (const float*)d_in[0];
    float* out = (float*)d_out;

    // total output pixels = 32*3*512*512 = 25,165,824 ; quads = 6,291,456
    const int n_quads = 32 * 3 * 512 * 128;
    const int block = 256;
    const int grid = (n_quads + block - 1) / block;  // 24576

    WaveletTransform_26104811225175_kernel<<<grid, block, 0, stream>>>(in, out, n_quads);
}

// Round 5
// 81.240 us; speedup vs baseline: 1.1271x; 1.1037x over previous
//
#include <hip/hip_runtime.h>

// out = 0.5f * (3a - b - c - d) over 2x2 input blocks.
// x: (32,3,1024,1024) f32  ->  out: (32,3,512,512) f32
//
// Wave-dense layout: each wave owns a 2KB even-row segment + 2KB odd-row
// segment (256 output cols). All 4 load instructions are perfectly dense 1KB
// (lane stride 16B = access width), nontemporal. Each lane computes two
// float2 results (cols 2l,2l+1 and 128+2l,128+2l+1), then an 8-shuffle
// gather packs lane l with cols 4l..4l+3 for one dense 16B store.
// (nt store is forbidden: bypasses L2, post-timing readback sees stale poison.)

typedef float f32x4 __attribute__((ext_vector_type(4)));

__global__ __launch_bounds__(256) void WaveletTransform_26104811225175_kernel(
    const float* __restrict__ in, float* __restrict__ out, int n_threads) {
    int p = blockIdx.x * blockDim.x + threadIdx.x;
    if (p >= n_threads) return;

    int l = p & 63;            // lane
    int w = p >> 6;            // global wave id
    int s  = w & 1;            // 256-col output segment within row (2 per row)
    int i  = (w >> 1) & 511;   // output row
    int bc = w >> 10;          // fused batch*channel (96)

    // element offsets
    size_t in_base  = ((size_t)bc << 20) + ((size_t)(i << 1) << 10) + ((size_t)s << 9) + ((size_t)l << 2);
    size_t out_base = ((size_t)bc << 18) + ((size_t)i << 9) + ((size_t)s << 8) + ((size_t)l << 2);

    const f32x4* E0 = reinterpret_cast<const f32x4*>(in + in_base);           // even row, first 1KB
    const f32x4* E1 = reinterpret_cast<const f32x4*>(in + in_base + 256);     // even row, second 1KB
    const f32x4* O0 = reinterpret_cast<const f32x4*>(in + in_base + 1024);    // odd row, first 1KB
    const f32x4* O1 = reinterpret_cast<const f32x4*>(in + in_base + 1280);    // odd row, second 1KB

    f32x4 e0 = __builtin_nontemporal_load(E0);   // a,b,a,b  (cols 2l, 2l+1)
    f32x4 e1 = __builtin_nontemporal_load(E1);   // a,b,a,b  (cols 128+2l, 128+2l+1)
    f32x4 o0 = __builtin_nontemporal_load(O0);   // c,d,c,d
    f32x4 o1 = __builtin_nontemporal_load(O1);   // c,d,c,d

    // r_even: output cols {2l, 2l+1}; r_odd: {128+2l, 128+2l+1}
    float rex = 0.5f * (3.0f * e0.x - e0.y - o0.x - o0.y);
    float rey = 0.5f * (3.0f * e0.z - e0.w - o0.z - o0.w);
    float rox = 0.5f * (3.0f * e1.x - e1.y - o1.x - o1.y);
    float roy = 0.5f * (3.0f * e1.z - e1.w - o1.z - o1.w);

    // Gather: lane l stores cols 4l..4l+3.
    //   l < 32:  cols < 128  -> r_even of lanes 2l, 2l+1
    //   l >= 32: cols >= 128 -> r_odd  of lanes 2l-64, 2l-63
    int i0 = (2 * l) & 63;
    int i1 = (2 * l + 1) & 63;
    float ax = __shfl(rex, i0), ay = __shfl(rey, i0);
    float az = __shfl(rex, i1), aw = __shfl(rey, i1);
    float bx = __shfl(rox, i0), by = __shfl(roy, i0);
    float bz = __shfl(rox, i1), bw = __shfl(roy, i1);

    bool lo = (l < 32);
    f32x4 r;
    r.x = lo ? ax : bx;
    r.y = lo ? ay : by;
    r.z = lo ? az : bz;
    r.w = lo ? aw : bw;

    *reinterpret_cast<f32x4*>(out + out_base) = r;
}

extern "C" void kernel_launch(void* const* d_in, const int* in_sizes, int n_in,
                              void* d_out, int out_size, void* d_ws, size_t ws_size,
                              hipStream_t stream) {
    const float* in = (const float*)d_in[0];
    float* out = (float*)d_out;

    // 96 bc * 512 rows * 2 segments * 64 lanes = 6,291,456 threads
    const int n_threads = 96 * 512 * 2 * 64;
    const int block = 256;
    const int grid = (n_threads + block - 1) / block;  // 24576

    WaveletTransform_26104811225175_kernel<<<grid, block, 0, stream>>>(in, out, n_threads);
}